// Round 6
// baseline (36.025 us; speedup 1.0000x reference)
//
#include <hip/hip_runtime.h>
#include <hip/hip_bf16.h>

typedef __attribute__((ext_vector_type(8)))  short    short8;
typedef __attribute__((ext_vector_type(16))) float    f32x16;
typedef __attribute__((ext_vector_type(4)))  unsigned uint4v;
typedef __attribute__((ext_vector_type(2)))  unsigned uint2v;

#define K_DIM    4096
#define N_DIM    16384
#define WORDS_N  512
#define KBLKS    (K_DIM / 32)        // 128 transposed word-rows per plane

// Truncate two fp32 (raw bits) to one dword of two packed bf16.
__device__ __forceinline__ unsigned pack_bf16(unsigned hi, unsigned lo) {
    return __builtin_amdgcn_perm(hi, lo, 0x07060302u);
}

// ---------------- Kernel T: 32x32 bit-transpose of both planes ----------------
// in : plane[k][wcol] word, bit b -> column wcol*32+b
// out : planeT[kblk][n] word, bit j -> k = kblk*32+j
// Per block: 64 k x 64 wcol panel of one plane. Lane-parallel butterfly:
// lanes j of a 32-half hold the 32 input words of one tile.
__global__ __launch_bounds__(256)
void transpose_planes(const unsigned* __restrict__ Bnz,
                      const unsigned* __restrict__ Bsg,
                      unsigned* __restrict__ BTnz,
                      unsigned* __restrict__ BTsg)
{
    __shared__ unsigned sm[64][65];   // pad 65: read col -> bank (j+c)&31, conflict-free

    const int bid  = blockIdx.x;                  // 1024 = 2 planes x 64 kpan x 8 wcpan
    const int p    = bid >> 9;
    const int kpan = (bid >> 3) & 63;             // 64 k's each
    const int wcp0 = (bid & 7) * 64;              // 64 word-cols each
    const unsigned* src = p ? Bsg : Bnz;
    unsigned* dst       = p ? BTsg : BTnz;

    const int t  = threadIdx.x;
    const int r  = t >> 2;                        // 0..63 k-row
    const int c0 = (t & 3) * 16;                  // 16 words per thread
    #pragma unroll
    for (int i = 0; i < 4; ++i) {
        uint4v v = *(const uint4v*)(src + (size_t)(kpan * 64 + r) * WORDS_N + wcp0 + c0 + i * 4);
        sm[r][c0 + i * 4 + 0] = v[0];
        sm[r][c0 + i * 4 + 1] = v[1];
        sm[r][c0 + i * 4 + 2] = v[2];
        sm[r][c0 + i * 4 + 3] = v[3];
    }
    __syncthreads();

    const int lane = t & 63;
    const int wv   = t >> 6;          // 4 waves x 16 reg-tasks = 64 tasks = 128 tiles
    const int half = lane >> 5;
    const int j    = lane & 31;

    for (int q8 = 0; q8 < 16; ++q8) {
        const int q   = wv * 16 + q8;             // task id
        const int kb  = q >> 5;                   // 0..1 local kblk
        const int wcp = q & 31;                   // word-col pair
        const int wcl = wcp * 2 + half;

        unsigned x = sm[kb * 32 + j][wcl];

        // 5-step bit-matrix transpose across the 32-lane half.
        #pragma unroll
        for (int st = 0; st < 5; ++st) {
            const int s = 1 << st;
            const unsigned m = (st == 0) ? 0x55555555u : (st == 1) ? 0x33333333u :
                               (st == 2) ? 0x0F0F0F0Fu : (st == 3) ? 0x00FF00FFu : 0x0000FFFFu;
            unsigned y = __shfl_xor(x, s, 64);
            unsigned lo = (x & m)  | ((y << s) & ~m);   // (lane&s)==0 side
            unsigned hi = (x & ~m) | ((y >> s) & m);    // (lane&s)!=0 side
            x = (lane & s) ? hi : lo;
        }
        // lane j now holds output word for column n = (wcp0+wcl)*32 + j
        dst[(size_t)(kpan * 2 + kb) * N_DIM + (wcp0 + wcl) * 32 + j] = x;
    }
}

// ---------------- Kernel XP: pre-pack x into MFMA-fragment order --------------
// xf[(kb16*2 + h)*32 + b] : 16B = bf16 x[row b][kb16*16 + h*8 .. +8]
__global__ __launch_bounds__(256)
void xprep(const unsigned* __restrict__ x32, uint4v* __restrict__ xf)
{
    const int gid = blockIdx.x * 256 + threadIdx.x;   // 16384
    const int b   = gid & 31;
    const int h   = (gid >> 5) & 1;
    const int kb  = gid >> 6;
    const unsigned* src = x32 + (size_t)b * K_DIM + kb * 16 + h * 8;
    uint4v a0 = *(const uint4v*)src;
    uint4v a1 = *(const uint4v*)(src + 4);
    uint4v pk;
    pk[0] = pack_bf16(a0[1], a0[0]);
    pk[1] = pack_bf16(a0[3], a0[2]);
    pk[2] = pack_bf16(a1[1], a1[0]);
    pk[3] = pack_bf16(a1[3], a1[2]);
    xf[gid] = pk;
}

// ---------------- Kernel G: barrier-free register-streaming GEMM -------------
// Decode 8 k-bits from private words -> 4 dwords of packed bf16 B-operand.
__device__ __forceinline__ void dec8(unsigned nzw, unsigned sgw, int pshift,
                                     unsigned out[4]) {
    const unsigned nb = (nzw >> pshift) & 0xFFu;
    const unsigned sb = (sgw >> pshift) & 0xFFu;
    #pragma unroll
    for (int jj = 0; jj < 4; ++jj) {
        unsigned b0 = (nb >> (2 * jj)) & 1u;
        unsigned b1 = (nb >> (2 * jj + 1)) & 1u;
        unsigned s0 = (sb >> (2 * jj)) & 1u;
        unsigned s1 = (sb >> (2 * jj + 1)) & 1u;
        out[jj] = b0 * 0x3F80u | b1 * 0x3F800000u | (s0 << 15) | (s1 << 31);
    }
}

template<int KSPLIT>
__global__ __launch_bounds__(512, 4)
void gemm_bt(const uint4v* __restrict__ xf,
             const unsigned* __restrict__ BTnz,
             const unsigned* __restrict__ BTsg,
             float* __restrict__ partial)      // [KSPLIT][32][N]
{
    constexpr int KT = K_DIM / KSPLIT;         // 512
    constexpr int NCH = KT / 64;               // 8 chunks of 64 k

    const int bid = blockIdx.x;
    const int nb  = (bid & 7) * 8 + ((bid >> 3) & 7);   // 0..63, XCD-grouped
    const int kb  = bid >> 6;                           // 0..KSPLIT-1
    const int tid = threadIdx.x;
    const int lane = tid & 63;
    const int wv   = tid >> 6;
    const int h    = lane >> 5;
    const int b    = lane & 31;

    const int wc = nb * 8 + wv;               // word-column owned by this wave
    const int n0 = wc * 32;

    const unsigned* nzp = BTnz + n0 + b;      // + kblk*N_DIM per k-block
    const unsigned* sgp = BTsg + n0 + b;
    const int kblk0 = kb * (KT / 32);

    f32x16 acc{};

    // preload chunk 0 (2 k-blocks x 2 planes)
    unsigned nz0 = nzp[(size_t)kblk0 * N_DIM];
    unsigned nz1 = nzp[(size_t)(kblk0 + 1) * N_DIM];
    unsigned sg0 = sgp[(size_t)kblk0 * N_DIM];
    unsigned sg1 = sgp[(size_t)(kblk0 + 1) * N_DIM];

    for (int c = 0; c < NCH; ++c) {
        unsigned nn0 = 0, nn1 = 0, ns0 = 0, ns1 = 0;
        if (c + 1 < NCH) {                    // issue next-chunk loads early
            const int kn = kblk0 + (c + 1) * 2;
            nn0 = nzp[(size_t)kn * N_DIM];
            nn1 = nzp[(size_t)(kn + 1) * N_DIM];
            ns0 = sgp[(size_t)kn * N_DIM];
            ns1 = sgp[(size_t)(kn + 1) * N_DIM];
        }

        const int kst0 = kb * 32 + c * 4;     // global 16-k step index base
        #pragma unroll
        for (int s = 0; s < 4; ++s) {
            uint4v af4 = xf[(size_t)((kst0 + s) * 2 + h) * 32 + b];
            union { unsigned u[4]; short8 v; } aa;
            aa.u[0] = af4[0]; aa.u[1] = af4[1]; aa.u[2] = af4[2]; aa.u[3] = af4[3];

            const unsigned nzw = (s < 2) ? nz0 : nz1;
            const unsigned sgw = (s < 2) ? sg0 : sg1;
            const int p = (s & 1) * 16 + h * 8;
            union { unsigned u[4]; short8 v; } bb;
            dec8(nzw, sgw, p, bb.u);

            acc = __builtin_amdgcn_mfma_f32_32x32x16_bf16(aa.v, bb.v, acc, 0, 0, 0);
        }
        nz0 = nn0; nz1 = nn1; sg0 = ns0; sg1 = ns1;
    }

    // C/D layout: col = lane&31, row = (r&3) + 8*(r>>2) + 4*(lane>>5)
    #pragma unroll
    for (int r = 0; r < 16; ++r) {
        const int row = (r & 3) + 8 * (r >> 2) + 4 * h;
        partial[((size_t)(kb * 32 + row)) * N_DIM + n0 + b] = acc[r];
    }
}

// ---------------- Kernel R: K-split reduce + bias + ReLU ---------------------
template<int KSPLIT>
__global__ __launch_bounds__(256)
void pass2(const float* __restrict__ partial, const float* __restrict__ bias,
           float* __restrict__ out)
{
    const int gid = blockIdx.x * 256 + threadIdx.x;    // one float2 each
    const int m   = gid >> 13;
    const int n2  = gid & 8191;
    const size_t off = (size_t)m * N_DIM + (size_t)n2 * 2;
    float sx = 0.f, sy = 0.f;
    #pragma unroll
    for (int s = 0; s < KSPLIT; ++s) {
        const float2 p = *(const float2*)(partial + (size_t)s * 32 * N_DIM + off);
        sx += p.x; sy += p.y;
    }
    const float2 bv = *(const float2*)(bias + (size_t)n2 * 2);
    float2 y;
    y.x = sx + bv.x; y.x = y.x < 0.f ? 0.f : y.x;
    y.y = sy + bv.y; y.y = y.y < 0.f ? 0.f : y.y;
    *(float2*)(out + off) = y;
}

extern "C" void kernel_launch(void* const* d_in, const int* in_sizes, int n_in,
                              void* d_out, int out_size, void* d_ws, size_t ws_size,
                              hipStream_t stream) {
    const unsigned* x32 = (const unsigned*)d_in[0];   // fp32 bits [32][4096]
    const unsigned* nz  = (const unsigned*)d_in[1];
    const unsigned* sg  = (const unsigned*)d_in[2];
    const float* bias   = (const float*)d_in[3];
    float* out          = (float*)d_out;

    // ws layout: [0,16MB) partials ; [16,24) BTnz ; [24,32) BTsg ; [32,32.25) xf
    char* ws = (char*)d_ws;
    float*    part = (float*)ws;
    unsigned* BTnz = (unsigned*)(ws + (size_t)16 * 1024 * 1024);
    unsigned* BTsg = (unsigned*)(ws + (size_t)24 * 1024 * 1024);
    uint4v*   xf   = (uint4v*)  (ws + (size_t)32 * 1024 * 1024);

    transpose_planes<<<1024, 256, 0, stream>>>(nz, sg, BTnz, BTsg);
    xprep<<<64, 256, 0, stream>>>(x32, xf);
    gemm_bt<8><<<512, 512, 0, stream>>>(xf, BTnz, BTsg, part);
    pass2<8><<<1024, 256, 0, stream>>>(part, bias, out);
}

// Round 7
// 28.977 us; speedup vs baseline: 1.2432x; 1.2432x over previous
//
#include <hip/hip_runtime.h>
#include <hip/hip_bf16.h>

typedef __attribute__((ext_vector_type(8)))  short    short8;
typedef __attribute__((ext_vector_type(16))) float    f32x16;
typedef __attribute__((ext_vector_type(4)))  unsigned uint4v;

#define K_DIM    4096
#define N_DIM    16384
#define WORDS_N  512

// Truncate two fp32 (raw bits) to one dword of two packed bf16.
__device__ __forceinline__ unsigned pack_bf16(unsigned hi, unsigned lo) {
    return __builtin_amdgcn_perm(hi, lo, 0x07060302u);
}

// ---------------- P: fused bit-transpose + x pre-pack (role-split) ----------
// transpose: plane[k][wcol] bit b -> planeT[kblk][n=wcol*32+b] bit j (k=kblk*32+j)
__global__ __launch_bounds__(256)
void prep(const unsigned* __restrict__ Bnz,
          const unsigned* __restrict__ Bsg,
          const unsigned* __restrict__ x32,
          unsigned* __restrict__ BTnz,
          unsigned* __restrict__ BTsg,
          uint4v* __restrict__ xf)
{
    __shared__ unsigned sm[64][65];
    const int bid = blockIdx.x;
    const int t   = threadIdx.x;

    if (bid >= 1024) {                    // ---- x pre-pack role (64 blocks)
        const int gid = (bid - 1024) * 256 + t;     // 16384
        const int bl  = gid & 31;
        const int hh  = (gid >> 5) & 1;
        const int kb  = gid >> 6;
        const unsigned* src = x32 + (size_t)bl * K_DIM + kb * 16 + hh * 8;
        uint4v a0 = *(const uint4v*)src;
        uint4v a1 = *(const uint4v*)(src + 4);
        uint4v pk;
        pk[0] = pack_bf16(a0[1], a0[0]);
        pk[1] = pack_bf16(a0[3], a0[2]);
        pk[2] = pack_bf16(a1[1], a1[0]);
        pk[3] = pack_bf16(a1[3], a1[2]);
        xf[gid] = pk;
        return;
    }

    // ---- transpose role: 1024 = 2 planes x 64 kpan x 8 wcpan
    const int p    = bid >> 9;
    const int kpan = (bid >> 3) & 63;
    const int wcp0 = (bid & 7) * 64;
    const unsigned* src = p ? Bsg : Bnz;
    unsigned* dst       = p ? BTsg : BTnz;

    const int r  = t >> 2;
    const int c0 = (t & 3) * 16;
    #pragma unroll
    for (int i = 0; i < 4; ++i) {
        uint4v v = *(const uint4v*)(src + (size_t)(kpan * 64 + r) * WORDS_N + wcp0 + c0 + i * 4);
        sm[r][c0 + i*4 + 0] = v[0];
        sm[r][c0 + i*4 + 1] = v[1];
        sm[r][c0 + i*4 + 2] = v[2];
        sm[r][c0 + i*4 + 3] = v[3];
    }
    __syncthreads();

    const int lane = t & 63;
    const int wvi  = t >> 6;
    const int half = lane >> 5;
    const int j    = lane & 31;

    // Per-lane butterfly constants: step = bperm + rotate + and + and_or.
    // side0: x=(x&m)|((y<<s)&~m) == (x&m)|(ror(y,32-s)&~m)  (wrap bits masked)
    // side1: x=(x&~m)|((y>>s)&m) == (x&~m)|(ror(y,s)&m)
    unsigned msel[5], rr[5];
    #pragma unroll
    for (int st = 0; st < 5; ++st) {
        const int s = 1 << st;
        const unsigned m = (st==0)?0x55555555u:(st==1)?0x33333333u:
                           (st==2)?0x0F0F0F0Fu:(st==3)?0x00FF00FFu:0x0000FFFFu;
        const unsigned full = (lane & s) ? 0xFFFFFFFFu : 0u;
        msel[st] = m ^ full;                       // keep-mask for x
        rr[st]   = (lane & s) ? (unsigned)s : (unsigned)(32 - s);
    }

    #pragma unroll 4
    for (int q8 = 0; q8 < 16; ++q8) {
        const int q   = wvi * 16 + q8;
        const int kbl = q >> 5;
        const int wcp = q & 31;
        const int wcl = wcp * 2 + half;

        unsigned xw = sm[kbl * 32 + j][wcl];
        #pragma unroll
        for (int st = 0; st < 5; ++st) {
            unsigned y = __shfl_xor(xw, 1 << st, 64);
            xw = (xw & msel[st]) |
                 (__builtin_amdgcn_alignbit(y, y, rr[st]) & ~msel[st]);
        }
        dst[(size_t)(kpan * 2 + kbl) * N_DIM + (wcp0 + wcl) * 32 + j] = xw;
    }
}

// ---------------- G: register-streaming GEMM, bf16 partials ------------------
// mul-spread decode: 8 k-bits (nz,sg) -> 4 dwords of packed bf16 {-1,0,+1}
__device__ __forceinline__ void dec8f(unsigned nzw, unsigned sgw, int p,
                                      unsigned out[4]) {
    const unsigned nb = (nzw >> p) & 0xFFu;
    const unsigned sb = (sgw >> p) & 0xFFu;
    const unsigned M = 0x00204081u, K1 = 0x01010101u;
    const unsigned t0 = ((nb & 0xFu) * M) & K1;    // bytes = nz bits 0..3
    const unsigned t1 = ((nb >> 4)   * M) & K1;
    const unsigned u0 = ((sb & 0xFu) * M) & K1;    // bytes = sg bits
    const unsigned u1 = ((sb >> 4)   * M) & K1;
    const unsigned hi0 = t0 * 63u + (u0 << 7);     // per-byte: n*0x3F + s*0x80
    const unsigned hi1 = t1 * 63u + (u1 << 7);
    const unsigned lo0 = t0 << 7;                  // per-byte: n*0x80
    const unsigned lo1 = t1 << 7;
    out[0] = __builtin_amdgcn_perm(hi0, lo0, 0x05010400u); // [lo.b0,hi.b0,lo.b1,hi.b1]
    out[1] = __builtin_amdgcn_perm(hi0, lo0, 0x07030602u);
    out[2] = __builtin_amdgcn_perm(hi1, lo1, 0x05010400u);
    out[3] = __builtin_amdgcn_perm(hi1, lo1, 0x07030602u);
}

__device__ __forceinline__ unsigned short f32_to_bf16_rne(float v) {
    unsigned u = __float_as_uint(v);
    return (unsigned short)((u + 0x7FFFu + ((u >> 16) & 1u)) >> 16);
}

template<int KSPLIT>
__global__ __launch_bounds__(512, 4)
void gemm_bt(const uint4v* __restrict__ xf,
             const unsigned* __restrict__ BTnz,
             const unsigned* __restrict__ BTsg,
             unsigned short* __restrict__ partial)   // bf16 [KSPLIT][32][N]
{
    constexpr int KT  = K_DIM / KSPLIT;        // 512
    constexpr int NCH = KT / 64;               // 8

    const int bid = blockIdx.x;
    const int nb  = (bid & 7) * 8 + ((bid >> 3) & 7);   // XCD = bid%8 = nb>>3
    const int kb  = bid >> 6;
    const int tid = threadIdx.x;
    const int lane = tid & 63;
    const int wv   = tid >> 6;
    const int h    = lane >> 5;
    const int bl   = lane & 31;

    const int wc = nb * 8 + wv;
    const int n0 = wc * 32;
    const unsigned* nzp = BTnz + n0 + bl;
    const unsigned* sgp = BTsg + n0 + bl;
    const int kblk0 = kb * (KT / 32);

    f32x16 acc{};

    // current-chunk registers (B words + 4 A-fragments), prefetched one ahead
    unsigned cn0, cn1, cs0, cs1;
    uint4v ca0, ca1, ca2, ca3;

    {   // prologue: chunk 0
        cn0 = nzp[(size_t)(kblk0 + 0) * N_DIM];
        cn1 = nzp[(size_t)(kblk0 + 1) * N_DIM];
        cs0 = sgp[(size_t)(kblk0 + 0) * N_DIM];
        cs1 = sgp[(size_t)(kblk0 + 1) * N_DIM];
        const int kst = kb * 32;
        ca0 = xf[(size_t)((kst + 0) * 2 + h) * 32 + bl];
        ca1 = xf[(size_t)((kst + 1) * 2 + h) * 32 + bl];
        ca2 = xf[(size_t)((kst + 2) * 2 + h) * 32 + bl];
        ca3 = xf[(size_t)((kst + 3) * 2 + h) * 32 + bl];
    }

    for (int c = 0; c < NCH; ++c) {
        unsigned pn0 = 0, pn1 = 0, ps0 = 0, ps1 = 0;
        uint4v pa0{}, pa1{}, pa2{}, pa3{};
        if (c + 1 < NCH) {                 // issue next-chunk loads early
            const int kn = kblk0 + (c + 1) * 2;
            pn0 = nzp[(size_t)kn * N_DIM];
            pn1 = nzp[(size_t)(kn + 1) * N_DIM];
            ps0 = sgp[(size_t)kn * N_DIM];
            ps1 = sgp[(size_t)(kn + 1) * N_DIM];
            const int kst = kb * 32 + (c + 1) * 4;
            pa0 = xf[(size_t)((kst + 0) * 2 + h) * 32 + bl];
            pa1 = xf[(size_t)((kst + 1) * 2 + h) * 32 + bl];
            pa2 = xf[(size_t)((kst + 2) * 2 + h) * 32 + bl];
            pa3 = xf[(size_t)((kst + 3) * 2 + h) * 32 + bl];
        }

        union { unsigned u[4]; short8 v; } aa, bb;
        // s = 0
        aa.u[0]=ca0[0]; aa.u[1]=ca0[1]; aa.u[2]=ca0[2]; aa.u[3]=ca0[3];
        dec8f(cn0, cs0, h * 8, bb.u);
        acc = __builtin_amdgcn_mfma_f32_32x32x16_bf16(aa.v, bb.v, acc, 0, 0, 0);
        // s = 1
        aa.u[0]=ca1[0]; aa.u[1]=ca1[1]; aa.u[2]=ca1[2]; aa.u[3]=ca1[3];
        dec8f(cn0, cs0, 16 + h * 8, bb.u);
        acc = __builtin_amdgcn_mfma_f32_32x32x16_bf16(aa.v, bb.v, acc, 0, 0, 0);
        // s = 2
        aa.u[0]=ca2[0]; aa.u[1]=ca2[1]; aa.u[2]=ca2[2]; aa.u[3]=ca2[3];
        dec8f(cn1, cs1, h * 8, bb.u);
        acc = __builtin_amdgcn_mfma_f32_32x32x16_bf16(aa.v, bb.v, acc, 0, 0, 0);
        // s = 3
        aa.u[0]=ca3[0]; aa.u[1]=ca3[1]; aa.u[2]=ca3[2]; aa.u[3]=ca3[3];
        dec8f(cn1, cs1, 16 + h * 8, bb.u);
        acc = __builtin_amdgcn_mfma_f32_32x32x16_bf16(aa.v, bb.v, acc, 0, 0, 0);

        cn0 = pn0; cn1 = pn1; cs0 = ps0; cs1 = ps1;
        ca0 = pa0; ca1 = pa1; ca2 = pa2; ca3 = pa3;
    }

    // C/D layout: col = lane&31, row = (r&3) + 8*(r>>2) + 4*(lane>>5)
    #pragma unroll
    for (int r = 0; r < 16; ++r) {
        const int row = (r & 3) + 8 * (r >> 2) + 4 * h;
        partial[((size_t)(kb * 32 + row)) * N_DIM + n0 + bl] = f32_to_bf16_rne(acc[r]);
    }
}

// ---------------- R: XCD-local K-split reduce + bias + ReLU ------------------
__global__ __launch_bounds__(256)
void reduce8(const unsigned* __restrict__ partial,  // bf16x2 dwords [8][32][N/2]
             const float* __restrict__ bias,
             float* __restrict__ out)
{
    const int bid = blockIdx.x;            // 1024
    const int x   = bid & 7;               // XCD that produced these columns
    const int q   = bid >> 3;              // 0..127
    const int m   = q >> 2;                // row 0..31
    const int c0  = x * 2048 + (q & 3) * 512;
    const int n   = c0 + threadIdx.x * 2;

    const size_t doff = ((size_t)m * N_DIM + n) >> 1;
    float sx = 0.f, sy = 0.f;
    #pragma unroll
    for (int s = 0; s < 8; ++s) {
        const unsigned d = partial[(size_t)s * (32 * N_DIM / 2) + doff];
        sx += __uint_as_float(d << 16);
        sy += __uint_as_float(d & 0xFFFF0000u);
    }
    const float2 bv = *(const float2*)(bias + n);
    float2 y;
    y.x = sx + bv.x; y.x = y.x < 0.f ? 0.f : y.x;
    y.y = sy + bv.y; y.y = y.y < 0.f ? 0.f : y.y;
    *(float2*)(out + (size_t)m * N_DIM + n) = y;
}

extern "C" void kernel_launch(void* const* d_in, const int* in_sizes, int n_in,
                              void* d_out, int out_size, void* d_ws, size_t ws_size,
                              hipStream_t stream) {
    const unsigned* x32 = (const unsigned*)d_in[0];   // fp32 bits [32][4096]
    const unsigned* nz  = (const unsigned*)d_in[1];
    const unsigned* sg  = (const unsigned*)d_in[2];
    const float* bias   = (const float*)d_in[3];
    float* out          = (float*)d_out;

    // ws: [0,8M) bf16 partials ; [8M,16M) BTnz ; [16M,24M) BTsg ; [24M,+256K) xf
    char* ws = (char*)d_ws;
    unsigned short* part = (unsigned short*)ws;
    unsigned* BTnz = (unsigned*)(ws + (size_t) 8 * 1024 * 1024);
    unsigned* BTsg = (unsigned*)(ws + (size_t)16 * 1024 * 1024);
    uint4v*   xf   = (uint4v*)  (ws + (size_t)24 * 1024 * 1024);

    prep<<<1088, 256, 0, stream>>>(nz, sg, x32, BTnz, BTsg, xf);
    gemm_bt<8><<<512, 512, 0, stream>>>(xf, BTnz, BTsg, part);
    reduce8<<<1024, 256, 0, stream>>>((const unsigned*)part, bias, out);
}

// Round 8
// 24.144 us; speedup vs baseline: 1.4921x; 1.2002x over previous
//
#include <hip/hip_runtime.h>
#include <hip/hip_bf16.h>

typedef __attribute__((ext_vector_type(8)))  short    short8;
typedef __attribute__((ext_vector_type(16))) float    f32x16;
typedef __attribute__((ext_vector_type(4)))  unsigned uint4v;

#define K_DIM    4096
#define N_DIM    16384
#define WORDS_N  512

// Truncate two fp32 (raw bits) to one dword of two packed bf16.
__device__ __forceinline__ unsigned pack_bf16(unsigned hi, unsigned lo) {
    return __builtin_amdgcn_perm(hi, lo, 0x07060302u);
}

// ---------------- P: fused bit-transpose + x pre-pack (role-split) ----------
// transpose: plane[k][wcol] bit b -> planeT[kblk][n=wcol*32+b] bit j (k=kblk*32+j)
__global__ __launch_bounds__(256)
void prep(const unsigned* __restrict__ Bnz,
          const unsigned* __restrict__ Bsg,
          const unsigned* __restrict__ x32,
          unsigned* __restrict__ BTnz,
          unsigned* __restrict__ BTsg,
          uint4v* __restrict__ xf)
{
    __shared__ unsigned sm[64][65];
    const int bid = blockIdx.x;
    const int t   = threadIdx.x;

    if (bid >= 1024) {                    // ---- x pre-pack role (64 blocks)
        const int gid = (bid - 1024) * 256 + t;     // 16384
        const int bl  = gid & 31;
        const int hh  = (gid >> 5) & 1;
        const int kb  = gid >> 6;
        const unsigned* src = x32 + (size_t)bl * K_DIM + kb * 16 + hh * 8;
        uint4v a0 = *(const uint4v*)src;
        uint4v a1 = *(const uint4v*)(src + 4);
        uint4v pk;
        pk[0] = pack_bf16(a0[1], a0[0]);
        pk[1] = pack_bf16(a0[3], a0[2]);
        pk[2] = pack_bf16(a1[1], a1[0]);
        pk[3] = pack_bf16(a1[3], a1[2]);
        xf[gid] = pk;
        return;
    }

    // ---- transpose role: 1024 = 2 planes x 64 kpan x 8 wcpan
    const int p    = bid >> 9;
    const int kpan = (bid >> 3) & 63;
    const int wcp0 = (bid & 7) * 64;      // wcpan == bid&7 == XCD -> matches gemm
    const unsigned* src = p ? Bsg : Bnz;
    unsigned* dst       = p ? BTsg : BTnz;

    const int r  = t >> 2;
    const int c0 = (t & 3) * 16;
    #pragma unroll
    for (int i = 0; i < 4; ++i) {
        uint4v v = *(const uint4v*)(src + (size_t)(kpan * 64 + r) * WORDS_N + wcp0 + c0 + i * 4);
        sm[r][c0 + i*4 + 0] = v[0];
        sm[r][c0 + i*4 + 1] = v[1];
        sm[r][c0 + i*4 + 2] = v[2];
        sm[r][c0 + i*4 + 3] = v[3];
    }
    __syncthreads();

    const int lane = t & 63;
    const int wvi  = t >> 6;
    const int half = lane >> 5;
    const int j    = lane & 31;

    // Butterfly constants. Steps 1,2,4: keep-mask + rotate amount.
    unsigned msel[3], rr[3];
    #pragma unroll
    for (int st = 0; st < 3; ++st) {
        const int s = 1 << st;
        const unsigned m = (st==0)?0x55555555u:(st==1)?0x33333333u:0x0F0F0F0Fu;
        const unsigned full = (lane & s) ? 0xFFFFFFFFu : 0u;
        msel[st] = m ^ full;
        rr[st]   = (lane & s) ? (unsigned)s : (unsigned)(32 - s);
    }
    // Steps 8,16: single v_perm with per-lane selector.
    // s=8 side0: [x.b0,y.b0,x.b2,y.b2] sel=0x02060004 ; side1: [y.b1,x.b1,y.b3,x.b3] sel=0x07030501
    // s=16 side0: [x.b0,x.b1,y.b0,y.b1] sel=0x01000504 ; side1: [y.b2,y.b3,x.b2,x.b3] sel=0x07060302
    const unsigned sel8  = (lane & 8)  ? 0x07030501u : 0x02060004u;
    const unsigned sel16 = (lane & 16) ? 0x07060302u : 0x01000504u;

    #pragma unroll 4
    for (int q8 = 0; q8 < 16; ++q8) {
        const int q   = wvi * 16 + q8;
        const int kbl = q >> 5;
        const int wcp = q & 31;
        const int wcl = wcp * 2 + half;

        unsigned xw = sm[kbl * 32 + j][wcl];
        #pragma unroll
        for (int st = 0; st < 3; ++st) {
            unsigned y = __shfl_xor(xw, 1 << st, 64);
            xw = (xw & msel[st]) |
                 (__builtin_amdgcn_alignbit(y, y, rr[st]) & ~msel[st]);
        }
        {
            unsigned y = __shfl_xor(xw, 8, 64);
            xw = __builtin_amdgcn_perm(xw, y, sel8);
            y = __shfl_xor(xw, 16, 64);
            xw = __builtin_amdgcn_perm(xw, y, sel16);
        }
        dst[(size_t)(kpan * 2 + kbl) * N_DIM + (wcp0 + wcl) * 32 + j] = xw;
    }
}

// ---------------- G: register-streaming GEMM + in-block K-reduce -------------
// mul-spread decode: 8 k-bits (nz,sg) -> 4 dwords of packed bf16 {-1,0,+1}
__device__ __forceinline__ void dec8f(unsigned nzw, unsigned sgw, int p,
                                      unsigned out[4]) {
    const unsigned nb = (nzw >> p) & 0xFFu;
    const unsigned sb = (sgw >> p) & 0xFFu;
    const unsigned M = 0x00204081u, K1 = 0x01010101u;
    const unsigned t0 = ((nb & 0xFu) * M) & K1;
    const unsigned t1 = ((nb >> 4)   * M) & K1;
    const unsigned u0 = ((sb & 0xFu) * M) & K1;
    const unsigned u1 = ((sb >> 4)   * M) & K1;
    const unsigned hi0 = t0 * 63u + (u0 << 7);     // per-byte: n*0x3F + s*0x80
    const unsigned hi1 = t1 * 63u + (u1 << 7);
    const unsigned lo0 = t0 << 7;                  // per-byte: n*0x80
    const unsigned lo1 = t1 << 7;
    out[0] = __builtin_amdgcn_perm(hi0, lo0, 0x05010400u);
    out[1] = __builtin_amdgcn_perm(hi0, lo0, 0x07030602u);
    out[2] = __builtin_amdgcn_perm(hi1, lo1, 0x05010400u);
    out[3] = __builtin_amdgcn_perm(hi1, lo1, 0x07030602u);
}

__global__ __launch_bounds__(512, 4)
void gemm_fused(const uint4v* __restrict__ xf,
                const unsigned* __restrict__ BTnz,
                const unsigned* __restrict__ BTsg,
                const float* __restrict__ bias,
                float* __restrict__ out)
{
    __shared__ float red[8][1024];             // 32 KB: 8 partial 32x32 tiles

    const int bid = blockIdx.x;                // 512 blocks, one word-column each
    const int wc  = (bid & 7) * 64 + (bid >> 3);    // XCD = bid&7 = wc>>6
    const int n0  = wc * 32;
    const int tid = threadIdx.x;
    const int lane = tid & 63;
    const int wv   = tid >> 6;                 // wave owns k-range [wv*512, wv*512+512)
    const int h    = lane >> 5;
    const int bl   = lane & 31;

    const unsigned* nzp = BTnz + n0 + bl;
    const unsigned* sgp = BTsg + n0 + bl;
    const int kblk0 = wv * 16;

    f32x16 acc{};

    unsigned cn0, cn1, cs0, cs1;
    uint4v ca0, ca1, ca2, ca3;

    {   // prologue: chunk 0
        cn0 = nzp[(size_t)(kblk0 + 0) * N_DIM];
        cn1 = nzp[(size_t)(kblk0 + 1) * N_DIM];
        cs0 = sgp[(size_t)(kblk0 + 0) * N_DIM];
        cs1 = sgp[(size_t)(kblk0 + 1) * N_DIM];
        const int kst = wv * 32;
        ca0 = xf[(size_t)((kst + 0) * 2 + h) * 32 + bl];
        ca1 = xf[(size_t)((kst + 1) * 2 + h) * 32 + bl];
        ca2 = xf[(size_t)((kst + 2) * 2 + h) * 32 + bl];
        ca3 = xf[(size_t)((kst + 3) * 2 + h) * 32 + bl];
    }

    for (int c = 0; c < 8; ++c) {
        unsigned pn0 = 0, pn1 = 0, ps0 = 0, ps1 = 0;
        uint4v pa0{}, pa1{}, pa2{}, pa3{};
        if (c + 1 < 8) {                       // issue next-chunk loads early
            const int kn = kblk0 + (c + 1) * 2;
            pn0 = nzp[(size_t)kn * N_DIM];
            pn1 = nzp[(size_t)(kn + 1) * N_DIM];
            ps0 = sgp[(size_t)kn * N_DIM];
            ps1 = sgp[(size_t)(kn + 1) * N_DIM];
            const int kst = wv * 32 + (c + 1) * 4;
            pa0 = xf[(size_t)((kst + 0) * 2 + h) * 32 + bl];
            pa1 = xf[(size_t)((kst + 1) * 2 + h) * 32 + bl];
            pa2 = xf[(size_t)((kst + 2) * 2 + h) * 32 + bl];
            pa3 = xf[(size_t)((kst + 3) * 2 + h) * 32 + bl];
        }

        union { unsigned u[4]; short8 v; } aa, bb;
        aa.u[0]=ca0[0]; aa.u[1]=ca0[1]; aa.u[2]=ca0[2]; aa.u[3]=ca0[3];
        dec8f(cn0, cs0, h * 8, bb.u);
        acc = __builtin_amdgcn_mfma_f32_32x32x16_bf16(aa.v, bb.v, acc, 0, 0, 0);
        aa.u[0]=ca1[0]; aa.u[1]=ca1[1]; aa.u[2]=ca1[2]; aa.u[3]=ca1[3];
        dec8f(cn0, cs0, 16 + h * 8, bb.u);
        acc = __builtin_amdgcn_mfma_f32_32x32x16_bf16(aa.v, bb.v, acc, 0, 0, 0);
        aa.u[0]=ca2[0]; aa.u[1]=ca2[1]; aa.u[2]=ca2[2]; aa.u[3]=ca2[3];
        dec8f(cn1, cs1, h * 8, bb.u);
        acc = __builtin_amdgcn_mfma_f32_32x32x16_bf16(aa.v, bb.v, acc, 0, 0, 0);
        aa.u[0]=ca3[0]; aa.u[1]=ca3[1]; aa.u[2]=ca3[2]; aa.u[3]=ca3[3];
        dec8f(cn1, cs1, 16 + h * 8, bb.u);
        acc = __builtin_amdgcn_mfma_f32_32x32x16_bf16(aa.v, bb.v, acc, 0, 0, 0);

        cn0 = pn0; cn1 = pn1; cs0 = ps0; cs1 = ps1;
        ca0 = pa0; ca1 = pa1; ca2 = pa2; ca3 = pa3;
    }

    // Per-wave partial tile -> LDS.
    // C/D layout: col = lane&31, row = (r&3) + 8*(r>>2) + 4*(lane>>5)
    #pragma unroll
    for (int r = 0; r < 16; ++r) {
        const int row = (r & 3) + 8 * (r >> 2) + 4 * h;
        red[wv][row * 32 + bl] = acc[r];
    }
    __syncthreads();

    // 8-way K reduction + bias + ReLU + fp32 store. 2 outputs/thread.
    const int i0 = tid * 2;
    float sx = 0.f, sy = 0.f;
    #pragma unroll
    for (int s = 0; s < 8; ++s) {
        const float2 p = *(const float2*)&red[s][i0];
        sx += p.x;
        sy += p.y;
    }
    const int m  = tid >> 4;            // output row 0..31
    const int nn = i0 & 31;             // even column within tile
    const float2 bv = *(const float2*)(bias + n0 + nn);
    float2 y;
    y.x = sx + bv.x; y.x = y.x < 0.f ? 0.f : y.x;
    y.y = sy + bv.y; y.y = y.y < 0.f ? 0.f : y.y;
    *(float2*)(out + (size_t)m * N_DIM + n0 + nn) = y;
}

extern "C" void kernel_launch(void* const* d_in, const int* in_sizes, int n_in,
                              void* d_out, int out_size, void* d_ws, size_t ws_size,
                              hipStream_t stream) {
    const unsigned* x32 = (const unsigned*)d_in[0];   // fp32 bits [32][4096]
    const unsigned* nz  = (const unsigned*)d_in[1];
    const unsigned* sg  = (const unsigned*)d_in[2];
    const float* bias   = (const float*)d_in[3];
    float* out          = (float*)d_out;

    // ws: [0,8M) BTnz ; [8M,16M) BTsg ; [16M,+256K) xf
    char* ws = (char*)d_ws;
    unsigned* BTnz = (unsigned*)ws;
    unsigned* BTsg = (unsigned*)(ws + (size_t) 8 * 1024 * 1024);
    uint4v*   xf   = (uint4v*)  (ws + (size_t)16 * 1024 * 1024);

    prep<<<1088, 256, 0, stream>>>(nz, sg, x32, BTnz, BTsg, xf);
    gemm_fused<<<512, 512, 0, stream>>>(xf, BTnz, BTsg, bias, out);
}